// Round 1
// baseline (362.425 us; speedup 1.0000x reference)
//
#include <hip/hip_runtime.h>

constexpr int NUM_HEADS      = 32;
constexpr int HEAD_DIM       = 128;
constexpr int NUM_KV         = 8;
constexpr int GROUP          = 4;                      // query heads per kv head
constexpr int BLOCK_SIZE     = 16;
constexpr int BLOCKS_PER_SEQ = 64;
constexpr int BATCH          = 64;
constexpr int SEQ            = BLOCKS_PER_SEQ * BLOCK_SIZE;  // 1024
constexpr int KV_ROW         = NUM_KV * HEAD_DIM;            // 1024 floats per slot-row
constexpr float SCALE        = 0.08838834764831845f;

// One workgroup (256 threads = 4 waves) per (batch, kv_head).
// Phase 1: scores for 4 group-heads; Phase 2: softmax; Phase 3: P*V.
__global__ __launch_bounds__(256) void paged_attn_kernel(
    const float* __restrict__ q,            // [B, 32, 128]
    const float* __restrict__ knew,         // [B, 8, 128]
    const float* __restrict__ vnew,         // [B, 8, 128]
    const float* __restrict__ kcache,       // [4096, 16, 8, 128]
    const float* __restrict__ vcache,       // [4096, 16, 8, 128]
    const int*   __restrict__ slot_mapping, // [B]
    const int*   __restrict__ block_tables, // [B, 64]
    float*       __restrict__ out)          // [B, 32*128]
{
    const int b    = (int)blockIdx.x >> 3;
    const int kvh  = (int)blockIdx.x & 7;
    const int tid  = (int)threadIdx.x;
    const int lane = tid & 63;
    const int wave = tid >> 6;

    __shared__ int   s_row[SEQ];         // >=0: cache slot-row; <0: override, idx = -1-r
    __shared__ float s_sc[GROUP][SEQ];   // scores -> probs (16 KB)
    __shared__ float s_inv[GROUP];
    __shared__ int   s_bt[BLOCKS_PER_SEQ];
    __shared__ int   s_slot[BATCH];

    if (tid < BLOCKS_PER_SEQ) s_bt[tid] = block_tables[b * BLOCKS_PER_SEQ + tid];
    if (tid >= 64 && tid < 64 + BATCH) s_slot[tid - 64] = slot_mapping[tid - 64];
    __syncthreads();

    // Per-token source row: cache slot, or redirect to fresh k/v (reference
    // scatters new tokens into the cache before the gather; we must not
    // mutate the input cache, so we redirect reads instead).
    for (int t = tid; t < SEQ; t += 256) {
        int slot = s_bt[t >> 4] * BLOCK_SIZE + (t & 15);
        int r = slot;
        #pragma unroll 8
        for (int i = 0; i < BATCH; ++i)
            if (s_slot[i] == slot) r = -1 - i;
        s_row[t] = r;
    }

    const int h0 = kvh * GROUP;
    float2 qf[GROUP];
    #pragma unroll
    for (int g = 0; g < GROUP; ++g)
        qf[g] = *reinterpret_cast<const float2*>(
            &q[((size_t)b * NUM_HEADS + h0 + g) * HEAD_DIM + lane * 2]);
    __syncthreads();

    // ---- Phase 1: scores[g][t] = SCALE * dot(q[g], K[t]) ----
    for (int t = wave; t < SEQ; t += 4) {
        int r = s_row[t];
        const float* krow = (r >= 0)
            ? kcache + (size_t)r * KV_ROW + kvh * HEAD_DIM
            : knew   + (size_t)(-1 - r) * KV_ROW + kvh * HEAD_DIM;
        float2 kv2 = *reinterpret_cast<const float2*>(&krow[lane * 2]);
        float p0 = qf[0].x * kv2.x + qf[0].y * kv2.y;
        float p1 = qf[1].x * kv2.x + qf[1].y * kv2.y;
        float p2 = qf[2].x * kv2.x + qf[2].y * kv2.y;
        float p3 = qf[3].x * kv2.x + qf[3].y * kv2.y;
        #pragma unroll
        for (int off = 1; off < 64; off <<= 1) {
            p0 += __shfl_xor(p0, off);
            p1 += __shfl_xor(p1, off);
            p2 += __shfl_xor(p2, off);
            p3 += __shfl_xor(p3, off);
        }
        if (lane == 0) {
            s_sc[0][t] = p0 * SCALE;
            s_sc[1][t] = p1 * SCALE;
            s_sc[2][t] = p2 * SCALE;
            s_sc[3][t] = p3 * SCALE;
        }
    }
    __syncthreads();

    // ---- Phase 2: per-head softmax over S=1024 (one wave per head) ----
    {
        const int g = wave;
        float m = -1e30f;
        for (int t = lane; t < SEQ; t += 64) m = fmaxf(m, s_sc[g][t]);
        #pragma unroll
        for (int off = 32; off; off >>= 1) m = fmaxf(m, __shfl_xor(m, off));
        float sum = 0.f;
        for (int t = lane; t < SEQ; t += 64) {
            float e = __expf(s_sc[g][t] - m);
            s_sc[g][t] = e;
            sum += e;
        }
        #pragma unroll
        for (int off = 32; off; off >>= 1) sum += __shfl_xor(sum, off);
        if (lane == 0) s_inv[g] = 1.0f / sum;
    }
    __syncthreads();

    // ---- Phase 3: O[g][d] = (1/l) * sum_t P[g][t] * V[t][d] ----
    // wave = head g; lane covers 2 dims; all 4 waves stream the same V row
    // (same addresses -> L1 broadcast), float2 coalesced.
    {
        const int g = wave;
        const int d = lane * 2;
        float accx = 0.f, accy = 0.f;
        #pragma unroll 4
        for (int t = 0; t < SEQ; ++t) {
            int r = s_row[t];
            const float* vrow = (r >= 0)
                ? vcache + (size_t)r * KV_ROW + kvh * HEAD_DIM
                : vnew   + (size_t)(-1 - r) * KV_ROW + kvh * HEAD_DIM;
            float2 vv = *reinterpret_cast<const float2*>(&vrow[d]);
            float p = s_sc[g][t];
            accx += p * vv.x;
            accy += p * vv.y;
        }
        float inv = s_inv[g];
        float2 o = make_float2(accx * inv, accy * inv);
        *reinterpret_cast<float2*>(
            &out[((size_t)b * NUM_HEADS + h0 + g) * HEAD_DIM + d]) = o;
    }
}

extern "C" void kernel_launch(void* const* d_in, const int* in_sizes, int n_in,
                              void* d_out, int out_size, void* d_ws, size_t ws_size,
                              hipStream_t stream) {
    const float* q    = (const float*)d_in[0];
    const float* knew = (const float*)d_in[1];
    const float* vnew = (const float*)d_in[2];
    const float* kc   = (const float*)d_in[3];
    const float* vc   = (const float*)d_in[4];
    const int*   slot = (const int*)d_in[5];
    const int*   bt   = (const int*)d_in[6];
    float* out = (float*)d_out;

    dim3 grid(BATCH * NUM_KV);   // 512 workgroups: one per (batch, kv_head)
    dim3 block(256);
    hipLaunchKernelGGL(paged_attn_kernel, grid, block, 0, stream,
                       q, knew, vnew, kc, vc, slot, bt, out);
}

// Round 2
// 120.866 us; speedup vs baseline: 2.9986x; 2.9986x over previous
//
#include <hip/hip_runtime.h>

constexpr int NUM_HEADS      = 32;
constexpr int HEAD_DIM       = 128;
constexpr int NUM_KV         = 8;
constexpr int GROUP          = 4;                     // query heads per kv head
constexpr int BLOCK_SIZE     = 16;
constexpr int BLOCKS_PER_SEQ = 64;
constexpr int BATCH          = 64;
constexpr int SEQ            = BLOCKS_PER_SEQ * BLOCK_SIZE;   // 1024
constexpr int KV_ROW         = NUM_KV * HEAD_DIM;             // 1024 floats / slot-row
constexpr int SPLIT          = 8;                    // flash-decode partitions
constexpr int TOK            = SEQ / SPLIT;          // 128 tokens per partition
constexpr int BLKS           = TOK / BLOCK_SIZE;     // 8 table entries per partition
constexpr float SCALE        = 0.08838834764831845f;

// workspace layout (floats): unnormalized partial O, then m, then l
constexpr size_t WS_O = 0;
constexpr size_t WS_M = (size_t)BATCH * NUM_KV * SPLIT * GROUP * HEAD_DIM; // 2,097,152
constexpr size_t WS_L = WS_M + (size_t)BATCH * NUM_KV * SPLIT * GROUP;     // +16,384
// total = 2,130,944 floats = 8.5 MB of d_ws

// One wg (256 thr = 4 waves) per (b, kv_head, split): partial flash-attention.
__global__ __launch_bounds__(256) void paged_attn_split(
    const float* __restrict__ q,            // [B, 32, 128]
    const float* __restrict__ knew,         // [B, 8, 128]
    const float* __restrict__ vnew,         // [B, 8, 128]
    const float* __restrict__ kcache,       // [4096, 16, 8, 128]
    const float* __restrict__ vcache,       // [4096, 16, 8, 128]
    const int*   __restrict__ slot_mapping, // [B]
    const int*   __restrict__ block_tables, // [B, 64]
    float*       __restrict__ ws)
{
    const int wg  = (int)blockIdx.x;        // ((b*KV + kvh)*SPLIT + sp)
    const int sp  = wg & (SPLIT - 1);
    const int bk  = wg >> 3;                // b*KV + kvh
    const int kvh = bk & 7;
    const int b   = bk >> 3;
    const int tid = (int)threadIdx.x;
    const int lane = tid & 63;
    const int wave = tid >> 6;
    const int sub  = lane >> 4;             // token sub-slot within wave (0..3)
    const int sl   = lane & 15;             // 16 lanes cooperate per token

    __shared__ int   s_row[TOK];            // >=0: cache slot-row; <0: override -1-i
    __shared__ float s_sc[GROUP][TOK];      // scores -> exp(score - m)
    __shared__ int   s_bt[BLKS];
    __shared__ int   s_slot[BATCH];

    if (tid < BLKS) s_bt[tid] = block_tables[b * BLOCKS_PER_SEQ + sp * BLKS + tid];
    if (tid >= 64 && tid < 64 + BATCH) s_slot[tid - 64] = slot_mapping[tid - 64];
    __syncthreads();

    // Token -> source row. Reference scatters fresh k/v into the cache before
    // the gather; we must not mutate inputs, so redirect reads instead.
    if (tid < TOK) {
        int slot = s_bt[tid >> 4] * BLOCK_SIZE + (tid & 15);
        int r = slot;
        #pragma unroll
        for (int i = 0; i < BATCH; ++i)
            if (s_slot[i] == slot) r = -1 - i;
        s_row[tid] = r;
    }

    const int h0 = kvh * GROUP;
    float4 qa[GROUP], qb[GROUP];            // q[g][sl*8 .. sl*8+8)
    #pragma unroll
    for (int g = 0; g < GROUP; ++g) {
        const float* qp = q + ((size_t)b * NUM_HEADS + h0 + g) * HEAD_DIM + sl * 8;
        qa[g] = *reinterpret_cast<const float4*>(qp);
        qb[g] = *reinterpret_cast<const float4*>(qp + 4);
    }
    __syncthreads();

    // ---- Phase 1: scores. 4 tokens/wave/iter, 16 lanes per token, f4 loads.
    for (int t = wave * 4 + sub; t < TOK; t += 16) {
        int r = s_row[t];
        const float* krow = (r >= 0)
            ? kcache + (size_t)r * KV_ROW + kvh * HEAD_DIM
            : knew   + (size_t)(-1 - r) * KV_ROW + kvh * HEAD_DIM;
        float4 ka = *reinterpret_cast<const float4*>(krow + sl * 8);
        float4 kb = *reinterpret_cast<const float4*>(krow + sl * 8 + 4);
        float p[GROUP];
        #pragma unroll
        for (int g = 0; g < GROUP; ++g) {
            p[g] = qa[g].x * ka.x + qa[g].y * ka.y + qa[g].z * ka.z + qa[g].w * ka.w
                 + qb[g].x * kb.x + qb[g].y * kb.y + qb[g].z * kb.z + qb[g].w * kb.w;
        }
        #pragma unroll
        for (int off = 1; off < 16; off <<= 1) {
            #pragma unroll
            for (int g = 0; g < GROUP; ++g) p[g] += __shfl_xor(p[g], off);
        }
        if (sl == 0) {
            #pragma unroll
            for (int g = 0; g < GROUP; ++g) s_sc[g][t] = p[g] * SCALE;
        }
    }
    __syncthreads();

    // ---- Phase 2: partial softmax stats over TOK=128 (wave = head) ----
    {
        const int g = wave;
        float v0 = s_sc[g][lane], v1 = s_sc[g][lane + 64];
        float m = fmaxf(v0, v1);
        #pragma unroll
        for (int off = 32; off; off >>= 1) m = fmaxf(m, __shfl_xor(m, off));
        float e0 = __expf(v0 - m), e1 = __expf(v1 - m);
        s_sc[g][lane] = e0;
        s_sc[g][lane + 64] = e1;
        float sum = e0 + e1;
        #pragma unroll
        for (int off = 32; off; off >>= 1) sum += __shfl_xor(sum, off);
        if (lane == 0) {
            ws[WS_M + (size_t)wg * GROUP + g] = m;
            ws[WS_L + (size_t)wg * GROUP + g] = sum;
        }
    }
    __syncthreads();

    // ---- Phase 3: unnormalized partial O (wave = head, lane = 2 dims) ----
    {
        const int g = wave;
        const int d = lane * 2;
        float ax = 0.f, ay = 0.f;
        #pragma unroll 4
        for (int t = 0; t < TOK; ++t) {
            int r = s_row[t];
            const float* vrow = (r >= 0)
                ? vcache + (size_t)r * KV_ROW + kvh * HEAD_DIM
                : vnew   + (size_t)(-1 - r) * KV_ROW + kvh * HEAD_DIM;
            float2 vv = *reinterpret_cast<const float2*>(vrow + d);
            float p = s_sc[g][t];
            ax += p * vv.x;
            ay += p * vv.y;
        }
        *reinterpret_cast<float2*>(
            ws + WS_O + ((size_t)wg * GROUP + g) * HEAD_DIM + d) = make_float2(ax, ay);
    }
}

// Log-sum-exp combine of SPLIT partials per (b, kvh, g). 2048 blocks x 128 thr.
__global__ __launch_bounds__(128) void paged_attn_combine(
    const float* __restrict__ ws, float* __restrict__ out)
{
    const int hb  = (int)blockIdx.x;        // (b*KV+kvh)*GROUP + g
    const int g   = hb & 3;
    const int bk  = hb >> 2;
    const int kvh = bk & 7;
    const int b   = bk >> 3;
    const int d   = (int)threadIdx.x;

    float m[SPLIT];
    float mstar = -1e30f;
    #pragma unroll
    for (int s = 0; s < SPLIT; ++s) {
        m[s] = ws[WS_M + ((size_t)(bk * SPLIT + s) * GROUP) + g];
        mstar = fmaxf(mstar, m[s]);
    }
    float L = 0.f, acc = 0.f;
    #pragma unroll
    for (int s = 0; s < SPLIT; ++s) {
        float w = __expf(m[s] - mstar);
        L   += w * ws[WS_L + ((size_t)(bk * SPLIT + s) * GROUP) + g];
        acc += w * ws[WS_O + ((size_t)(bk * SPLIT + s) * GROUP + g) * HEAD_DIM + d];
    }
    out[((size_t)b * NUM_HEADS + kvh * GROUP + g) * HEAD_DIM + d] = acc / L;
}

extern "C" void kernel_launch(void* const* d_in, const int* in_sizes, int n_in,
                              void* d_out, int out_size, void* d_ws, size_t ws_size,
                              hipStream_t stream) {
    const float* q    = (const float*)d_in[0];
    const float* knew = (const float*)d_in[1];
    const float* vnew = (const float*)d_in[2];
    const float* kc   = (const float*)d_in[3];
    const float* vc   = (const float*)d_in[4];
    const int*   slot = (const int*)d_in[5];
    const int*   bt   = (const int*)d_in[6];
    float* out = (float*)d_out;
    float* ws  = (float*)d_ws;   // needs 8.5 MB

    hipLaunchKernelGGL(paged_attn_split, dim3(BATCH * NUM_KV * SPLIT), dim3(256),
                       0, stream, q, knew, vnew, kc, vc, slot, bt, ws);
    hipLaunchKernelGGL(paged_attn_combine, dim3(BATCH * NUM_KV * GROUP), dim3(128),
                       0, stream, ws, out);
}

// Round 3
// 85.886 us; speedup vs baseline: 4.2198x; 1.4073x over previous
//
#include <hip/hip_runtime.h>

constexpr int NUM_HEADS      = 32;
constexpr int HEAD_DIM       = 128;
constexpr int NUM_KV         = 8;
constexpr int GROUP          = 4;                     // query heads per kv head
constexpr int BLOCK_SIZE     = 16;
constexpr int BLOCKS_PER_SEQ = 64;
constexpr int BATCH          = 64;
constexpr int SEQ            = BLOCKS_PER_SEQ * BLOCK_SIZE;   // 1024
constexpr int KV_ROW         = NUM_KV * HEAD_DIM;             // 1024 floats / slot-row
constexpr int SPLIT          = 8;                    // flash-decode partitions
constexpr int TOK            = SEQ / SPLIT;          // 128 tokens per partition
constexpr int BLKS           = TOK / BLOCK_SIZE;     // 8 table entries per partition
constexpr float SCALE        = 0.08838834764831845f;

// workspace layout (floats): unnormalized partial O, then m, then l
constexpr size_t WS_O = 0;
constexpr size_t WS_M = (size_t)BATCH * NUM_KV * SPLIT * GROUP * HEAD_DIM; // 2,097,152
constexpr size_t WS_L = WS_M + (size_t)BATCH * NUM_KV * SPLIT * GROUP;     // +16,384

// One wg (256 thr = 4 waves) per (b, kv_head, split): partial flash-attention.
__global__ __launch_bounds__(256) void paged_attn_split(
    const float* __restrict__ q,            // [B, 32, 128]
    const float* __restrict__ knew,         // [B, 8, 128]
    const float* __restrict__ vnew,         // [B, 8, 128]
    const float* __restrict__ kcache,       // [4096, 16, 8, 128]
    const float* __restrict__ vcache,       // [4096, 16, 8, 128]
    const int*   __restrict__ slot_mapping, // [B]
    const int*   __restrict__ block_tables, // [B, 64]
    float*       __restrict__ ws)
{
    const int wg  = (int)blockIdx.x;        // ((b*KV + kvh)*SPLIT + sp)
    const int sp  = wg & (SPLIT - 1);
    const int bk  = wg >> 3;                // b*KV + kvh
    const int kvh = bk & 7;
    const int b   = bk >> 3;
    const int tid = (int)threadIdx.x;
    const int lane = tid & 63;
    const int wave = tid >> 6;

    __shared__ int   s_row[TOK];              // >=0: cache slot-row; <0: override -1-i
    __shared__ float s_p[TOK][GROUP];         // scores -> exp(score - m), [t][g]
    __shared__ float s_o[4][GROUP][HEAD_DIM]; // per-wave partial O (8 KB)
    __shared__ int   s_bt[BLKS];
    __shared__ int   s_slot[BATCH];

    if (tid < BLKS) s_bt[tid] = block_tables[b * BLOCKS_PER_SEQ + sp * BLKS + tid];
    if (tid >= 64 && tid < 64 + BATCH) s_slot[tid - 64] = slot_mapping[tid - 64];
    __syncthreads();

    // Token -> source row. Reference scatters fresh k/v into the cache before
    // the gather; we must not mutate inputs, so redirect reads instead.
    if (tid < TOK) {
        int slot = s_bt[tid >> 4] * BLOCK_SIZE + (tid & 15);
        int r = slot;
        #pragma unroll
        for (int i = 0; i < BATCH; ++i)
            if (s_slot[i] == slot) r = -1 - i;
        s_row[tid] = r;
    }

    const int h0 = kvh * GROUP;
    const size_t hoff = (size_t)kvh * HEAD_DIM;
    const int sub = lane >> 4;              // token sub-slot within wave (0..3)
    const int sl  = lane & 15;              // 16 lanes cooperate per token

    float4 qa[GROUP], qb[GROUP];            // q[g][sl*8 .. sl*8+8)
    #pragma unroll
    for (int g = 0; g < GROUP; ++g) {
        const float* qp = q + ((size_t)b * NUM_HEADS + h0 + g) * HEAD_DIM + sl * 8;
        qa[g] = *reinterpret_cast<const float4*>(qp);
        qb[g] = *reinterpret_cast<const float4*>(qp + 4);
    }
    __syncthreads();

    // ---- Phase 1: scores. 4 tokens/wave/iter, 16 lanes per token, f4 loads.
    #pragma unroll
    for (int t = wave * 4 + sub; t < TOK; t += 16) {
        int r = s_row[t];
        const float* krow = (r >= 0)
            ? kcache + (size_t)r * KV_ROW + hoff
            : knew   + (size_t)(-1 - r) * KV_ROW + hoff;
        float4 ka = *reinterpret_cast<const float4*>(krow + sl * 8);
        float4 kb = *reinterpret_cast<const float4*>(krow + sl * 8 + 4);
        float p[GROUP];
        #pragma unroll
        for (int g = 0; g < GROUP; ++g) {
            p[g] = qa[g].x * ka.x + qa[g].y * ka.y + qa[g].z * ka.z + qa[g].w * ka.w
                 + qb[g].x * kb.x + qb[g].y * kb.y + qb[g].z * kb.z + qb[g].w * kb.w;
        }
        #pragma unroll
        for (int off = 1; off < 16; off <<= 1) {
            #pragma unroll
            for (int g = 0; g < GROUP; ++g) p[g] += __shfl_xor(p[g], off);
        }
        if (sl == 0) {
            #pragma unroll
            for (int g = 0; g < GROUP; ++g) s_p[t][g] = p[g] * SCALE;
        }
    }
    __syncthreads();

    // ---- Phase 2: partial softmax stats over TOK=128 (wave = head) ----
    {
        const int g = wave;
        float v0 = s_p[lane][g], v1 = s_p[lane + 64][g];
        float m = fmaxf(v0, v1);
        #pragma unroll
        for (int off = 32; off; off >>= 1) m = fmaxf(m, __shfl_xor(m, off));
        float e0 = __expf(v0 - m), e1 = __expf(v1 - m);
        s_p[lane][g] = e0;
        s_p[lane + 64][g] = e1;
        float sum = e0 + e1;
        #pragma unroll
        for (int off = 32; off; off >>= 1) sum += __shfl_xor(sum, off);
        if (lane == 0) {
            ws[WS_M + (size_t)wg * GROUP + g] = m;
            ws[WS_L + (size_t)wg * GROUP + g] = sum;
        }
    }
    __syncthreads();

    // ---- Phase 3: unnormalized partial O. Tokens partitioned across waves
    // (no duplicate loads); half-wave per V row, float4/lane; acc = 4 dims x
    // 4 heads in registers; cross-half shfl + cross-wave LDS reduce at end.
    {
        const int half = lane >> 5;         // which of 2 tokens this iter
        const int dl   = lane & 31;         // dim-lane: dims [dl*4, dl*4+4)
        float4 a0 = {0,0,0,0}, a1 = a0, a2 = a0, a3 = a0;
        #pragma unroll 8
        for (int i = 0; i < TOK / 8; ++i) { // 16 iters, 2 tokens/iter/wave
            int t = wave * (TOK / 4) + i * 2 + half;
            int r = s_row[t];
            const float* vrow = (r >= 0)
                ? vcache + (size_t)r * KV_ROW + hoff
                : vnew   + (size_t)(-1 - r) * KV_ROW + hoff;
            float4 vv = *reinterpret_cast<const float4*>(vrow + dl * 4);
            float4 pv = *reinterpret_cast<const float4*>(&s_p[t][0]); // broadcast
            a0.x += pv.x * vv.x; a0.y += pv.x * vv.y; a0.z += pv.x * vv.z; a0.w += pv.x * vv.w;
            a1.x += pv.y * vv.x; a1.y += pv.y * vv.y; a1.z += pv.y * vv.z; a1.w += pv.y * vv.w;
            a2.x += pv.z * vv.x; a2.y += pv.z * vv.y; a2.z += pv.z * vv.z; a2.w += pv.z * vv.w;
            a3.x += pv.w * vv.x; a3.y += pv.w * vv.y; a3.z += pv.w * vv.z; a3.w += pv.w * vv.w;
        }
        // combine the two token-halves: lane d gets lane d+32's partial
        #define RED4(A) A.x += __shfl_xor(A.x, 32); A.y += __shfl_xor(A.y, 32); \
                        A.z += __shfl_xor(A.z, 32); A.w += __shfl_xor(A.w, 32);
        RED4(a0) RED4(a1) RED4(a2) RED4(a3)
        #undef RED4
        if (half == 0) {
            *reinterpret_cast<float4*>(&s_o[wave][0][dl * 4]) = a0;
            *reinterpret_cast<float4*>(&s_o[wave][1][dl * 4]) = a1;
            *reinterpret_cast<float4*>(&s_o[wave][2][dl * 4]) = a2;
            *reinterpret_cast<float4*>(&s_o[wave][3][dl * 4]) = a3;
        }
    }
    __syncthreads();

    // cross-wave reduce + store partial O: thread owns (g=wave, 2 dims)
    {
        const int g = wave;
        const int d = lane * 2;
        float ox = 0.f, oy = 0.f;
        #pragma unroll
        for (int w = 0; w < 4; ++w) {
            ox += s_o[w][g][d];
            oy += s_o[w][g][d + 1];
        }
        *reinterpret_cast<float2*>(
            ws + WS_O + ((size_t)wg * GROUP + g) * HEAD_DIM + d) = make_float2(ox, oy);
    }
}

// Log-sum-exp combine of SPLIT partials per (b, kvh, g). 2048 blocks x 128 thr.
__global__ __launch_bounds__(128) void paged_attn_combine(
    const float* __restrict__ ws, float* __restrict__ out)
{
    const int hb  = (int)blockIdx.x;        // (b*KV+kvh)*GROUP + g
    const int g   = hb & 3;
    const int bk  = hb >> 2;
    const int kvh = bk & 7;
    const int b   = bk >> 3;
    const int d   = (int)threadIdx.x;

    float m[SPLIT];
    float mstar = -1e30f;
    #pragma unroll
    for (int s = 0; s < SPLIT; ++s) {
        m[s] = ws[WS_M + ((size_t)(bk * SPLIT + s) * GROUP) + g];
        mstar = fmaxf(mstar, m[s]);
    }
    float L = 0.f, acc = 0.f;
    #pragma unroll
    for (int s = 0; s < SPLIT; ++s) {
        float w = __expf(m[s] - mstar);
        L   += w * ws[WS_L + ((size_t)(bk * SPLIT + s) * GROUP) + g];
        acc += w * ws[WS_O + ((size_t)(bk * SPLIT + s) * GROUP + g) * HEAD_DIM + d];
    }
    out[((size_t)b * NUM_HEADS + kvh * GROUP + g) * HEAD_DIM + d] = acc / L;
}

extern "C" void kernel_launch(void* const* d_in, const int* in_sizes, int n_in,
                              void* d_out, int out_size, void* d_ws, size_t ws_size,
                              hipStream_t stream) {
    const float* q    = (const float*)d_in[0];
    const float* knew = (const float*)d_in[1];
    const float* vnew = (const float*)d_in[2];
    const float* kc   = (const float*)d_in[3];
    const float* vc   = (const float*)d_in[4];
    const int*   slot = (const int*)d_in[5];
    const int*   bt   = (const int*)d_in[6];
    float* out = (float*)d_out;
    float* ws  = (float*)d_ws;   // needs 8.5 MB

    hipLaunchKernelGGL(paged_attn_split, dim3(BATCH * NUM_KV * SPLIT), dim3(256),
                       0, stream, q, knew, vnew, kc, vc, slot, bt, ws);
    hipLaunchKernelGGL(paged_attn_combine, dim3(BATCH * NUM_KV * GROUP), dim3(128),
                       0, stream, ws, out);
}